// Round 4
// baseline (428.023 us; speedup 1.0000x reference)
//
#include <hip/hip_runtime.h>
#include <math.h>

#define NPART 32768
#define MS 50
#define BLOCK 128   // 2 waves = one hidden-split pair owning 16 particles

typedef __attribute__((ext_vector_type(8))) short bfrag;   // 8 bf16 (4 VGPRs)
typedef __attribute__((ext_vector_type(4))) float ffrag;   // 4 fp32 (MFMA C/D)

// float -> bf16 bits, round-to-nearest-even (staging / fallback)
__device__ __forceinline__ unsigned short f2bf(float x) {
    unsigned u = __float_as_uint(x);
    u += 0x7fffu + ((u >> 16) & 1u);
    return (unsigned short)(u >> 16);
}

#if __has_builtin(__builtin_amdgcn_cvt_pk_bf16_f32)
typedef __attribute__((ext_vector_type(2))) __bf16 bf16x2;
__device__ __forceinline__ unsigned pk2(float a, float b) {
    bf16x2 r = __builtin_amdgcn_cvt_pk_bf16_f32(a, b);
    return __builtin_bit_cast(unsigned, r);
}
#else
__device__ __forceinline__ unsigned pk2(float a, float b) {
    return (unsigned)f2bf(a) | ((unsigned)f2bf(b) << 16);
}
#endif

// tanh(x) = 1 - 2/(exp(2x)+1); saturates correctly at +/-inf.
__device__ __forceinline__ float fast_tanh(float x) {
    float e = __expf(2.0f * x);
    return 1.0f - __fdividef(2.0f, e + 1.0f);
}

// Pair split: wave w in {0,1} computes hidden rows [64w, 64w+64):
//   GEMM1: 4 M-tiles (mt = 4w + mt2), both K-tiles.
//   GEMM2: its own H half (kt2 in {0,1} -> hidden 64w + 32kt2) -> PARTIAL Z.
// H round-trip is wave-private (each wave reads only what it wrote).
// Z partials exchanged via double-buffered LDS + one __syncthreads per step.
// b2 enters through wave 0's GEMM2 C-init; wave 1 inits C = 0.
__global__ __launch_bounds__(BLOCK, 4)
void fused_sde_mfma(const float* __restrict__ obs,
                    const float* __restrict__ x0,
                    const float* __restrict__ v0,
                    const float* __restrict__ noise,
                    const float* __restrict__ gW1,
                    const float* __restrict__ gb1,
                    const float* __restrict__ gW2,
                    const float* __restrict__ gb2,
                    const float* __restrict__ gtheta,
                    const int* __restrict__ gobs_idx,
                    const int* __restrict__ gctrl,
                    float* __restrict__ outX,
                    float* __restrict__ outV)
{
    // H: per-wave 64 hidden, row pitch 72 shorts (144 B) -> <=2-way bank alias.
    // Z: [buf][srcwave][p][36 floats] (144 B pitch), double-buffered for WAR.
    __shared__ __align__(16) unsigned short Hlds[2][16][72];
    __shared__ __align__(16) float Zlds[2][2][16][36];

    const int tid  = threadIdx.x;
    const int w    = tid >> 6;       // wave in pair
    const int lane = tid & 63;
    const int p    = lane & 15;      // particle column
    const int q    = lane >> 4;      // quad
    const int part = blockIdx.x * 16 + p;
    const int mtb  = 4 * w;          // GEMM1 M-tile base (hidden 64w)

    // ---- weights into register A-fragments (one-time, per-wave half) ----
    bfrag A1[4][2];
    #pragma unroll
    for (int mt2 = 0; mt2 < 4; ++mt2) {
        const int h = 16 * (mtb + mt2) + p;
        #pragma unroll
        for (int kt = 0; kt < 2; ++kt) {
            bfrag a;
            #pragma unroll
            for (int j = 0; j < 8; ++j) {
                const int f = 32 * kt + 8 * q + j;
                const float wv = (f < 42) ? gW1[f * 128 + h] : 0.0f;
                a[j] = (short)f2bf(wv);
            }
            A1[mt2][kt] = a;
        }
    }
    bfrag A2[2][2];
    #pragma unroll
    for (int mt = 0; mt < 2; ++mt) {
        const int d = 16 * mt + p;
        #pragma unroll
        for (int kt2 = 0; kt2 < 2; ++kt2) {
            bfrag a;
            #pragma unroll
            for (int j = 0; j < 8; ++j)
                a[j] = (short)f2bf(gW2[(64 * w + 32 * kt2 + 8 * q + j) * 32 + d]);
            A2[mt][kt2] = a;
        }
    }

    // GEMM1 biases for this wave's 4 tiles (C-layout rows 4q+r)
    ffrag Bia1[4];
    #pragma unroll
    for (int mt2 = 0; mt2 < 4; ++mt2) {
        float4 b = *(const float4*)(gb1 + 16 * (mtb + mt2) + 4 * q);
        Bia1[mt2] = ffrag{b.x, b.y, b.z, b.w};
    }
    // GEMM2 C-init: wave 0 carries b2, wave 1 carries zero.
    ffrag Z0i = ffrag{0.f, 0.f, 0.f, 0.f}, Z1i = ffrag{0.f, 0.f, 0.f, 0.f};
    if (w == 0) {
        float4 b = *(const float4*)(gb2 + 4 * q);
        Z0i = ffrag{b.x, b.y, b.z, b.w};
        float4 c = *(const float4*)(gb2 + 16 + 4 * q);
        Z1i = ffrag{c.x, c.y, c.z, c.w};
    }

    const float theta = gtheta[0];
    const float tfeat = (float)gobs_idx[0];
    const float cr    = (float)gctrl[0];
    const float dt      = 1.0f / (float)MS;
    const float sqrt_dt = sqrtf(dt);
    const float ax  = 1.0f - dt * theta;
    const float bcr = dt * cr;
    const float kv  = dt * (0.5f - cr);

    // K-tile-1 B fragment: q0 = Y[0..7], q1 = [s, tfeat, 0...], q2/q3 = 0.
    bfrag BY = {0, 0, 0, 0, 0, 0, 0, 0};
    if (q == 0) {
        #pragma unroll
        for (int j = 0; j < 8; ++j) BY[j] = (short)f2bf(obs[j]);
    } else if (q == 1) {
        BY[1] = (short)f2bf(tfeat);
    }

    // ---- per-lane state: X dims [8q, 8q+8) of particle p (replicated per wave) ----
    float X[8];
    {
        const float4* xp = (const float4*)(x0 + (size_t)part * 32 + 8 * q);
        float4 a = xp[0], b = xp[1];
        X[0] = a.x; X[1] = a.y; X[2] = a.z; X[3] = a.w;
        X[4] = b.x; X[5] = b.y; X[6] = b.z; X[7] = b.w;
    }
    float V = v0[part];

    const float* nbase = noise + (size_t)part * 32 + 8 * q;
    unsigned short* hrow = &Hlds[w][p][0];

    #pragma unroll 1
    for (int m = 0; m < MS; ++m) {
        // this step's noise (used only after both GEMMs -> latency covered)
        const float* np = nbase + (size_t)m * ((size_t)NPART * 32);
        float4 n0 = ((const float4*)np)[0];
        float4 n1 = ((const float4*)np)[1];

        // B K-tile 0: X -> packed bf16
        int4 bxw = make_int4((int)pk2(X[0], X[1]), (int)pk2(X[2], X[3]),
                             (int)pk2(X[4], X[5]), (int)pk2(X[6], X[7]));
        bfrag BX = __builtin_bit_cast(bfrag, bxw);

        bfrag B1 = BY;
        if (q == 1) B1[0] = (short)f2bf((float)m * dt);

        // ---- GEMM1 (this wave's 4 tiles) + bias + tanh -> H (wave-private) ----
        #pragma unroll
        for (int mt2 = 0; mt2 < 4; ++mt2) {
            ffrag c = Bia1[mt2];
            c = __builtin_amdgcn_mfma_f32_16x16x32_bf16(A1[mt2][0], BX, c, 0, 0, 0);
            c = __builtin_amdgcn_mfma_f32_16x16x32_bf16(A1[mt2][1], B1, c, 0, 0, 0);
            const unsigned u0 = pk2(fast_tanh(c[0]), fast_tanh(c[1]));
            const unsigned u1 = pk2(fast_tanh(c[2]), fast_tanh(c[3]));
            *(uint2*)&hrow[16 * mt2 + 4 * q] = make_uint2(u0, u1);
        }

        __builtin_amdgcn_wave_barrier();   // DS in-order per wave; compiler fence

        // ---- GEMM2 over own H half -> partial Z ----
        ffrag C0 = Z0i, C1 = Z1i;
        #pragma unroll
        for (int kt2 = 0; kt2 < 2; ++kt2) {
            bfrag B2 = *(const bfrag*)&hrow[32 * kt2 + 8 * q];
            C0 = __builtin_amdgcn_mfma_f32_16x16x32_bf16(A2[0][kt2], B2, C0, 0, 0, 0);
            C1 = __builtin_amdgcn_mfma_f32_16x16x32_bf16(A2[1][kt2], B2, C1, 0, 0, 0);
        }

        // publish partial (C-layout), exchange, read both halves in B-layout
        float* zme = &Zlds[m & 1][w][p][0];
        *(ffrag*)&zme[4 * q]      = C0;
        *(ffrag*)&zme[16 + 4 * q] = C1;

        __syncthreads();

        const float* za = &Zlds[m & 1][0][p][0];
        const float* zb = &Zlds[m & 1][1][p][0];
        float4 a0 = *(const float4*)&za[8 * q];
        float4 a1 = *(const float4*)&za[8 * q + 4];
        float4 b0 = *(const float4*)&zb[8 * q];
        float4 b1 = *(const float4*)&zb[8 * q + 4];
        float Z[8] = {a0.x + b0.x, a0.y + b0.y, a0.z + b0.z, a0.w + b0.w,
                      a1.x + b1.x, a1.y + b1.y, a1.z + b1.z, a1.w + b1.w};
        float Nn[8] = {n0.x, n0.y, n0.z, n0.w, n1.x, n1.y, n1.z, n1.w};

        // V: (0.5-cr)*dt*sum(Z^2) + sqrt_dt*sum(Z*n)
        float s2 = 0.0f, sn = 0.0f;
        #pragma unroll
        for (int j = 0; j < 8; ++j) {
            s2 = fmaf(Z[j], Z[j], s2);
            sn = fmaf(Z[j], Nn[j], sn);
        }
        s2 += __shfl_xor(s2, 16); s2 += __shfl_xor(s2, 32);
        sn += __shfl_xor(sn, 16); sn += __shfl_xor(sn, 32);
        V = fmaf(kv, s2, fmaf(sqrt_dt, sn, V));

        // X = ax*X - bcr*Z + sqrt_dt*n
        #pragma unroll
        for (int j = 0; j < 8; ++j) {
            float t = fmaf(-bcr, Z[j], sqrt_dt * Nn[j]);
            X[j] = fmaf(ax, X[j], t);
        }
    }

    if (w == 0) {
        float4* xout = (float4*)(outX + (size_t)part * 32 + 8 * q);
        xout[0] = make_float4(X[0], X[1], X[2], X[3]);
        xout[1] = make_float4(X[4], X[5], X[6], X[7]);
        if (q == 0) outV[part] = V;
    }
}

extern "C" void kernel_launch(void* const* d_in, const int* in_sizes, int n_in,
                              void* d_out, int out_size, void* d_ws, size_t ws_size,
                              hipStream_t stream) {
    const float* obs   = (const float*)d_in[0];
    const float* x0    = (const float*)d_in[1];
    const float* v0    = (const float*)d_in[2];
    const float* noise = (const float*)d_in[3];
    const float* W1    = (const float*)d_in[4];
    const float* b1    = (const float*)d_in[5];
    const float* W2    = (const float*)d_in[6];
    const float* b2    = (const float*)d_in[7];
    const float* th    = (const float*)d_in[8];
    const int*   oi    = (const int*)d_in[9];
    const int*   cr    = (const int*)d_in[10];

    float* outX = (float*)d_out;
    float* outV = outX + (size_t)NPART * 32;

    dim3 grid(NPART / 16);   // 2048 blocks x 2 waves = 4096 waves (4/SIMD)
    fused_sde_mfma<<<grid, BLOCK, 0, stream>>>(obs, x0, v0, noise, W1, b1, W2, b2,
                                               th, oi, cr, outX, outV);
}

// Round 5
// 379.431 us; speedup vs baseline: 1.1281x; 1.1281x over previous
//
#include <hip/hip_runtime.h>
#include <math.h>

#define NPART 32768
#define MS 50
#define BLOCK 256

typedef __attribute__((ext_vector_type(8))) short bfrag;   // 8 bf16 (4 VGPRs)
typedef __attribute__((ext_vector_type(4))) float ffrag;   // 4 fp32 (MFMA C/D)

// float -> bf16 bits, round-to-nearest-even (staging / fallback)
__device__ __forceinline__ unsigned short f2bf(float x) {
    unsigned u = __float_as_uint(x);
    u += 0x7fffu + ((u >> 16) & 1u);
    return (unsigned short)(u >> 16);
}

#if __has_builtin(__builtin_amdgcn_cvt_pk_bf16_f32)
typedef __attribute__((ext_vector_type(2))) __bf16 bf16x2;
__device__ __forceinline__ unsigned pk2(float a, float b) {
    bf16x2 r = __builtin_amdgcn_cvt_pk_bf16_f32(a, b);
    return __builtin_bit_cast(unsigned, r);
}
#else
__device__ __forceinline__ unsigned pk2(float a, float b) {
    return (unsigned)f2bf(a) | ((unsigned)f2bf(b) << 16);
}
#endif

// tanh(x) = 1 - 2/(exp(2x)+1); saturates correctly at +/-inf.
__device__ __forceinline__ float fast_tanh(float x) {
    float e = __expf(2.0f * x);
    return 1.0f - __fdividef(2.0f, e + 1.0f);
}

// One wave = 16 particles (p = lane&15, q = lane>>4). Lane owns X dims
// [8q,8q+8) of particle p == B-layout of mfma_f32_16x16x32_bf16.
//
// Static-feature fold: pre-activation = W1x^T @ X  +  [b1 + W1y^T Y + t*W1t
// + s*W1s]  -- the bracket is per-hidden scalar; only s varies per step.
// So GEMM1 is ONE un-chained MFMA per M-tile (8 total), C-init computed by
// 4 FMAs/lane/tile at step start. GEMM2 split into two 2-deep chains.
// All LDS traffic wave-private; no __syncthreads in the loop.
__global__ __launch_bounds__(BLOCK, 2)
void fused_sde_mfma(const float* __restrict__ obs,
                    const float* __restrict__ x0,
                    const float* __restrict__ v0,
                    const float* __restrict__ noise,
                    const float* __restrict__ gW1,
                    const float* __restrict__ gb1,
                    const float* __restrict__ gW2,
                    const float* __restrict__ gb2,
                    const float* __restrict__ gtheta,
                    const int* __restrict__ gobs_idx,
                    const int* __restrict__ gctrl,
                    float* __restrict__ outX,
                    float* __restrict__ outV)
{
    __shared__ __align__(16) unsigned short Hlds[4][16][136];  // 272 B pitch
    __shared__ __align__(16) float Zlds[4][16][36];            // 144 B pitch

    const int tid  = threadIdx.x;
    const int w    = tid >> 6;
    const int lane = tid & 63;
    const int p    = lane & 15;
    const int q    = lane >> 4;
    const int part = blockIdx.x * 64 + w * 16 + p;

    const float theta = gtheta[0];
    const float tfeat = (float)gobs_idx[0];
    const float cr    = (float)gctrl[0];
    const float dt      = 1.0f / (float)MS;
    const float sqrt_dt = sqrtf(dt);
    const float ax  = 1.0f - dt * theta;
    const float bcr = dt * cr;
    const float kv  = dt * (0.5f - cr);

    // ---- A-fragments: W1 X-block only (features 0..31), one K-tile ----
    bfrag A1[8];
    #pragma unroll
    for (int mt = 0; mt < 8; ++mt) {
        const int h = 16 * mt + p;
        bfrag a;
        #pragma unroll
        for (int j = 0; j < 8; ++j)
            a[j] = (short)f2bf(gW1[(8 * q + j) * 128 + h]);
        A1[mt] = a;
    }
    bfrag A2[2][4];
    #pragma unroll
    for (int mt = 0; mt < 2; ++mt) {
        const int d = 16 * mt + p;
        #pragma unroll
        for (int kt = 0; kt < 4; ++kt) {
            bfrag a;
            #pragma unroll
            for (int j = 0; j < 8; ++j)
                a[j] = (short)f2bf(gW2[(32 * kt + 8 * q + j) * 32 + d]);
            A2[mt][kt] = a;
        }
    }

    // ---- static C-init (fp32): Stat[h] = b1 + Y.W1y + t*W1t ; W1s[h] ----
    // C-layout: lane (p,q) needs rows h = 16mt + 4q + r.
    ffrag Stat[8], W1s[8];
    #pragma unroll
    for (int mt = 0; mt < 8; ++mt) {
        #pragma unroll
        for (int r = 0; r < 4; ++r) {
            const int h = 16 * mt + 4 * q + r;
            float acc = gb1[h];
            #pragma unroll
            for (int j = 0; j < 8; ++j)
                acc = fmaf(obs[j], gW1[(32 + j) * 128 + h], acc);
            acc = fmaf(tfeat, gW1[41 * 128 + h], acc);
            Stat[mt][r] = acc;
            W1s[mt][r]  = gW1[40 * 128 + h];
        }
    }

    // GEMM2 C-inits from b2 (C-layout rows 4q+r)
    ffrag Z0i, Z1i;
    {
        float4 b = *(const float4*)(gb2 + 4 * q);
        Z0i = ffrag{b.x, b.y, b.z, b.w};
        float4 c = *(const float4*)(gb2 + 16 + 4 * q);
        Z1i = ffrag{c.x, c.y, c.z, c.w};
    }
    const ffrag Zzero = ffrag{0.f, 0.f, 0.f, 0.f};

    // ---- per-lane state ----
    float X[8];
    {
        const float4* xp = (const float4*)(x0 + (size_t)part * 32 + 8 * q);
        float4 a = xp[0], b = xp[1];
        X[0] = a.x; X[1] = a.y; X[2] = a.z; X[3] = a.w;
        X[4] = b.x; X[5] = b.y; X[6] = b.z; X[7] = b.w;
    }
    float V = v0[part];

    const float* nbase = noise + (size_t)part * 32 + 8 * q;
    float4 nc0 = ((const float4*)nbase)[0];
    float4 nc1 = ((const float4*)nbase)[1];

    unsigned short* hrow = &Hlds[w][p][0];
    float*          zrow = &Zlds[w][p][0];

    #pragma unroll 1
    for (int m = 0; m < MS; ++m) {
        const int mn = (m + 1 < MS) ? m + 1 : m;
        const float* np = nbase + (size_t)mn * ((size_t)NPART * 32);
        float4 nn0 = ((const float4*)np)[0];
        float4 nn1 = ((const float4*)np)[1];

        // B fragment: X -> packed bf16
        int4 bxw = make_int4((int)pk2(X[0], X[1]), (int)pk2(X[2], X[3]),
                             (int)pk2(X[4], X[5]), (int)pk2(X[6], X[7]));
        bfrag BX = __builtin_bit_cast(bfrag, bxw);

        const float s = (float)m * dt;

        // ---- GEMM1: C-init (ready at step start), 8 independent MFMAs ----
        ffrag C[8];
        #pragma unroll
        for (int mt = 0; mt < 8; ++mt) {
            ffrag c;
            #pragma unroll
            for (int r = 0; r < 4; ++r) c[r] = fmaf(s, W1s[mt][r], Stat[mt][r]);
            C[mt] = c;
        }
        #pragma unroll
        for (int mt = 0; mt < 8; ++mt)
            C[mt] = __builtin_amdgcn_mfma_f32_16x16x32_bf16(A1[mt], BX, C[mt], 0, 0, 0);

        #pragma unroll
        for (int mt = 0; mt < 8; ++mt) {
            const unsigned u0 = pk2(fast_tanh(C[mt][0]), fast_tanh(C[mt][1]));
            const unsigned u1 = pk2(fast_tanh(C[mt][2]), fast_tanh(C[mt][3]));
            *(uint2*)&hrow[16 * mt + 4 * q] = make_uint2(u0, u1);
        }

        __builtin_amdgcn_wave_barrier();   // DS in-order per wave

        // ---- GEMM2: two 2-deep chains per output tile ----
        bfrag B2[4];
        #pragma unroll
        for (int kt = 0; kt < 4; ++kt)
            B2[kt] = *(const bfrag*)&hrow[32 * kt + 8 * q];

        ffrag C0a = Z0i, C0b = Zzero, C1a = Z1i, C1b = Zzero;
        C0a = __builtin_amdgcn_mfma_f32_16x16x32_bf16(A2[0][0], B2[0], C0a, 0, 0, 0);
        C1a = __builtin_amdgcn_mfma_f32_16x16x32_bf16(A2[1][0], B2[0], C1a, 0, 0, 0);
        C0b = __builtin_amdgcn_mfma_f32_16x16x32_bf16(A2[0][2], B2[2], C0b, 0, 0, 0);
        C1b = __builtin_amdgcn_mfma_f32_16x16x32_bf16(A2[1][2], B2[2], C1b, 0, 0, 0);
        C0a = __builtin_amdgcn_mfma_f32_16x16x32_bf16(A2[0][1], B2[1], C0a, 0, 0, 0);
        C1a = __builtin_amdgcn_mfma_f32_16x16x32_bf16(A2[1][1], B2[1], C1a, 0, 0, 0);
        C0b = __builtin_amdgcn_mfma_f32_16x16x32_bf16(A2[0][3], B2[3], C0b, 0, 0, 0);
        C1b = __builtin_amdgcn_mfma_f32_16x16x32_bf16(A2[1][3], B2[3], C1b, 0, 0, 0);
        ffrag Cz0 = C0a + C0b;
        ffrag Cz1 = C1a + C1b;

        // Z: C-layout -> LDS -> B-layout (wave-private)
        *(ffrag*)&zrow[4 * q]      = Cz0;
        *(ffrag*)&zrow[16 + 4 * q] = Cz1;

        __builtin_amdgcn_wave_barrier();

        float4 z0 = *(const float4*)&zrow[8 * q];
        float4 z1 = *(const float4*)&zrow[8 * q + 4];
        float Z[8] = {z0.x, z0.y, z0.z, z0.w, z1.x, z1.y, z1.z, z1.w};
        float Nn[8] = {nc0.x, nc0.y, nc0.z, nc0.w, nc1.x, nc1.y, nc1.z, nc1.w};

        // V: (0.5-cr)*dt*sum(Z^2) + sqrt_dt*sum(Z*n)
        float s2 = 0.0f, sn = 0.0f;
        #pragma unroll
        for (int j = 0; j < 8; ++j) {
            s2 = fmaf(Z[j], Z[j], s2);
            sn = fmaf(Z[j], Nn[j], sn);
        }
        s2 += __shfl_xor(s2, 16); s2 += __shfl_xor(s2, 32);
        sn += __shfl_xor(sn, 16); sn += __shfl_xor(sn, 32);
        V = fmaf(kv, s2, fmaf(sqrt_dt, sn, V));

        // X = ax*X - bcr*Z + sqrt_dt*n
        #pragma unroll
        for (int j = 0; j < 8; ++j) {
            float t = fmaf(-bcr, Z[j], sqrt_dt * Nn[j]);
            X[j] = fmaf(ax, X[j], t);
        }

        nc0 = nn0; nc1 = nn1;
    }

    float4* xout = (float4*)(outX + (size_t)part * 32 + 8 * q);
    xout[0] = make_float4(X[0], X[1], X[2], X[3]);
    xout[1] = make_float4(X[4], X[5], X[6], X[7]);
    if (q == 0) outV[part] = V;
}

extern "C" void kernel_launch(void* const* d_in, const int* in_sizes, int n_in,
                              void* d_out, int out_size, void* d_ws, size_t ws_size,
                              hipStream_t stream) {
    const float* obs   = (const float*)d_in[0];
    const float* x0    = (const float*)d_in[1];
    const float* v0    = (const float*)d_in[2];
    const float* noise = (const float*)d_in[3];
    const float* W1    = (const float*)d_in[4];
    const float* b1    = (const float*)d_in[5];
    const float* W2    = (const float*)d_in[6];
    const float* b2    = (const float*)d_in[7];
    const float* th    = (const float*)d_in[8];
    const int*   oi    = (const int*)d_in[9];
    const int*   cr    = (const int*)d_in[10];

    float* outX = (float*)d_out;
    float* outV = outX + (size_t)NPART * 32;

    dim3 grid(NPART / 64);   // 512 blocks x 4 waves x 16 particles
    fused_sde_mfma<<<grid, BLOCK, 0, stream>>>(obs, x0, v0, noise, W1, b1, W2, b2,
                                               th, oi, cr, outX, outV);
}

// Round 6
// 373.016 us; speedup vs baseline: 1.1475x; 1.0172x over previous
//
#include <hip/hip_runtime.h>
#include <math.h>

#define NPART 32768
#define MS 50
#define BLOCK 256

typedef __attribute__((ext_vector_type(8))) short bfrag;   // 8 bf16 (4 VGPRs)
typedef __attribute__((ext_vector_type(4))) float ffrag;   // 4 fp32 (MFMA C/D)

// float -> bf16 bits, round-to-nearest-even (staging / fallback)
__device__ __forceinline__ unsigned short f2bf(float x) {
    unsigned u = __float_as_uint(x);
    u += 0x7fffu + ((u >> 16) & 1u);
    return (unsigned short)(u >> 16);
}

#if __has_builtin(__builtin_amdgcn_cvt_pk_bf16_f32)
typedef __attribute__((ext_vector_type(2))) __bf16 bf16x2;
__device__ __forceinline__ unsigned pk2(float a, float b) {
    bf16x2 r = __builtin_amdgcn_cvt_pk_bf16_f32(a, b);   // lo=a, hi=b
    return __builtin_bit_cast(unsigned, r);
}
#else
__device__ __forceinline__ unsigned pk2(float a, float b) {
    return (unsigned)f2bf(a) | ((unsigned)f2bf(b) << 16);
}
#endif

// tanh(x) = 1 - 2/(exp(2x)+1); saturates correctly at +/-inf.
__device__ __forceinline__ float fast_tanh(float x) {
    float e = __expf(2.0f * x);
    return 1.0f - __fdividef(2.0f, e + 1.0f);
}

// One wave = 16 particles (p = lane&15, q = lane>>4). Lane owns X dims
// [8q,8q+8) of particle p == B-layout of mfma_f32_16x16x32_bf16.
//
// GEMM1 (unchanged from R5): H(128x16) = W1x @ X + C-init(static fold).
//   C-layout: lane(p,q), tile mt, reg r holds H[16mt+4q+r][particle p].
//
// GEMM2 *layout trick*: computed as Z^T(16x32) = H^T(16x16...) with H as the
// A-OPERAND. A-layout A[m=lane&15][k=8q+j] has the same 16-index (=particle)
// mapping as GEMM1's C-output column, so the tanh'd C-regs feed GEMM2
// directly: A-frag(kt) element j = C[2kt+(j>>2)][j&3], which holds hidden
// unit kappa = 32kt+16(j>>2)+4q+(j&3). W2's B-frags are loaded kappa-permuted
// at init so the contraction is exact. NO H LDS round-trip, NO barrier.
// D-output: lane(p,q) reg r = Z[particle 4q+r][outdim 16nt+p]; a small
// scatter/gather through LDS returns Z to the X-update (B-) layout.
__global__ __launch_bounds__(BLOCK, 2)
void fused_sde_mfma(const float* __restrict__ obs,
                    const float* __restrict__ x0,
                    const float* __restrict__ v0,
                    const float* __restrict__ noise,
                    const float* __restrict__ gW1,
                    const float* __restrict__ gb1,
                    const float* __restrict__ gW2,
                    const float* __restrict__ gb2,
                    const float* __restrict__ gtheta,
                    const int* __restrict__ gobs_idx,
                    const int* __restrict__ gctrl,
                    float* __restrict__ outX,
                    float* __restrict__ outV)
{
    // Zlds[wave][particle][dim], pitch 36 floats (144 B) -> <=2-way aliasing.
    __shared__ __align__(16) float Zlds[4][16][36];

    const int tid  = threadIdx.x;
    const int w    = tid >> 6;
    const int lane = tid & 63;
    const int p    = lane & 15;
    const int q    = lane >> 4;
    const int part = blockIdx.x * 64 + w * 16 + p;

    const float theta = gtheta[0];
    const float tfeat = (float)gobs_idx[0];
    const float cr    = (float)gctrl[0];
    const float dt      = 1.0f / (float)MS;
    const float sqrt_dt = sqrtf(dt);
    const float ax  = 1.0f - dt * theta;
    const float bcr = dt * cr;
    const float kv  = dt * (0.5f - cr);

    // ---- GEMM1 A-fragments: W1 X-block (features 0..31) ----
    bfrag A1[8];
    #pragma unroll
    for (int mt = 0; mt < 8; ++mt) {
        const int h = 16 * mt + p;
        bfrag a;
        #pragma unroll
        for (int j = 0; j < 8; ++j)
            a[j] = (short)f2bf(gW1[(8 * q + j) * 128 + h]);
        A1[mt] = a;
    }

    // ---- GEMM2 B-fragments: W2 rows kappa-permuted, cols = outdim 16nt+p ----
    bfrag B2[2][4];
    #pragma unroll
    for (int nt = 0; nt < 2; ++nt) {
        #pragma unroll
        for (int kt = 0; kt < 4; ++kt) {
            bfrag b;
            #pragma unroll
            for (int j = 0; j < 8; ++j) {
                const int h = 32 * kt + 16 * (j >> 2) + 4 * q + (j & 3);  // kappa
                b[j] = (short)f2bf(gW2[h * 32 + 16 * nt + p]);
            }
            B2[nt][kt] = b;
        }
    }

    // ---- static C-init for GEMM1: Stat[h] = b1 + Y.W1y + t*W1t ; W1s[h] ----
    ffrag Stat[8], W1s[8];
    #pragma unroll
    for (int mt = 0; mt < 8; ++mt) {
        #pragma unroll
        for (int r = 0; r < 4; ++r) {
            const int h = 16 * mt + 4 * q + r;
            float acc = gb1[h];
            #pragma unroll
            for (int j = 0; j < 8; ++j)
                acc = fmaf(obs[j], gW1[(32 + j) * 128 + h], acc);
            acc = fmaf(tfeat, gW1[41 * 128 + h], acc);
            Stat[mt][r] = acc;
            W1s[mt][r]  = gW1[40 * 128 + h];
        }
    }

    // GEMM2 C-init: b2[outdim 16nt+p], broadcast across the 4 particle-rows.
    const float bz0 = gb2[p], bz1 = gb2[16 + p];
    const ffrag Z0i = ffrag{bz0, bz0, bz0, bz0};
    const ffrag Z1i = ffrag{bz1, bz1, bz1, bz1};
    const ffrag Zzero = ffrag{0.f, 0.f, 0.f, 0.f};

    // ---- per-lane state ----
    float X[8];
    {
        const float4* xp = (const float4*)(x0 + (size_t)part * 32 + 8 * q);
        float4 a = xp[0], b = xp[1];
        X[0] = a.x; X[1] = a.y; X[2] = a.z; X[3] = a.w;
        X[4] = b.x; X[5] = b.y; X[6] = b.z; X[7] = b.w;
    }
    float V = v0[part];

    const float* nbase = noise + (size_t)part * 32 + 8 * q;
    float4 nc0 = ((const float4*)nbase)[0];
    float4 nc1 = ((const float4*)nbase)[1];

    float* zbase = &Zlds[w][0][0];
    const float* zrow = &Zlds[w][p][0];

    #pragma unroll 1
    for (int m = 0; m < MS; ++m) {
        const int mn = (m + 1 < MS) ? m + 1 : m;
        const float* np = nbase + (size_t)mn * ((size_t)NPART * 32);
        float4 nn0 = ((const float4*)np)[0];
        float4 nn1 = ((const float4*)np)[1];

        // B fragment: X -> packed bf16
        int4 bxw = make_int4((int)pk2(X[0], X[1]), (int)pk2(X[2], X[3]),
                             (int)pk2(X[4], X[5]), (int)pk2(X[6], X[7]));
        bfrag BX = __builtin_bit_cast(bfrag, bxw);

        const float s = (float)m * dt;

        // ---- GEMM1: 8 independent MFMAs, C-init ready at step start ----
        ffrag C[8];
        #pragma unroll
        for (int mt = 0; mt < 8; ++mt) {
            ffrag c;
            #pragma unroll
            for (int r = 0; r < 4; ++r) c[r] = fmaf(s, W1s[mt][r], Stat[mt][r]);
            C[mt] = c;
        }
        #pragma unroll
        for (int mt = 0; mt < 8; ++mt)
            C[mt] = __builtin_amdgcn_mfma_f32_16x16x32_bf16(A1[mt], BX, C[mt], 0, 0, 0);

        // ---- tanh + pack: C-regs become GEMM2 A-fragments directly ----
        uint2 Hpk[8];
        #pragma unroll
        for (int mt = 0; mt < 8; ++mt) {
            const unsigned u0 = pk2(fast_tanh(C[mt][0]), fast_tanh(C[mt][1]));
            const unsigned u1 = pk2(fast_tanh(C[mt][2]), fast_tanh(C[mt][3]));
            Hpk[mt] = make_uint2(u0, u1);
        }

        // ---- GEMM2: Z^T = H^T @ W2(kappa), two 2-deep chains per N-tile ----
        ffrag D0a = Z0i, D0b = Zzero, D1a = Z1i, D1b = Zzero;
        #pragma unroll
        for (int kt = 0; kt < 4; ++kt) {
            int4 aw = make_int4((int)Hpk[2 * kt].x, (int)Hpk[2 * kt].y,
                                (int)Hpk[2 * kt + 1].x, (int)Hpk[2 * kt + 1].y);
            bfrag A = __builtin_bit_cast(bfrag, aw);
            if (kt & 1) {
                D0b = __builtin_amdgcn_mfma_f32_16x16x32_bf16(A, B2[0][kt], D0b, 0, 0, 0);
                D1b = __builtin_amdgcn_mfma_f32_16x16x32_bf16(A, B2[1][kt], D1b, 0, 0, 0);
            } else {
                D0a = __builtin_amdgcn_mfma_f32_16x16x32_bf16(A, B2[0][kt], D0a, 0, 0, 0);
                D1a = __builtin_amdgcn_mfma_f32_16x16x32_bf16(A, B2[1][kt], D1a, 0, 0, 0);
            }
        }
        ffrag D0 = D0a + D0b;   // Z[particle 4q+r][outdim p]
        ffrag D1 = D1a + D1b;   // Z[particle 4q+r][outdim 16+p]

        // ---- scatter Z to [particle][dim], gather back in B-layout ----
        #pragma unroll
        for (int r = 0; r < 4; ++r) {
            float* zr = zbase + (4 * q + r) * 36;
            zr[p]      = D0[r];     // compiler fuses into ds_write2_b32
            zr[16 + p] = D1[r];
        }

        __builtin_amdgcn_wave_barrier();   // DS in-order per wave

        float4 z0 = *(const float4*)&zrow[8 * q];
        float4 z1 = *(const float4*)&zrow[8 * q + 4];
        float Z[8] = {z0.x, z0.y, z0.z, z0.w, z1.x, z1.y, z1.z, z1.w};
        float Nn[8] = {nc0.x, nc0.y, nc0.z, nc0.w, nc1.x, nc1.y, nc1.z, nc1.w};

        // V: (0.5-cr)*dt*sum(Z^2) + sqrt_dt*sum(Z*n)
        float s2 = 0.0f, sn = 0.0f;
        #pragma unroll
        for (int j = 0; j < 8; ++j) {
            s2 = fmaf(Z[j], Z[j], s2);
            sn = fmaf(Z[j], Nn[j], sn);
        }
        s2 += __shfl_xor(s2, 16); s2 += __shfl_xor(s2, 32);
        sn += __shfl_xor(sn, 16); sn += __shfl_xor(sn, 32);
        V = fmaf(kv, s2, fmaf(sqrt_dt, sn, V));

        // X = ax*X - bcr*Z + sqrt_dt*n
        #pragma unroll
        for (int j = 0; j < 8; ++j) {
            float t = fmaf(-bcr, Z[j], sqrt_dt * Nn[j]);
            X[j] = fmaf(ax, X[j], t);
        }

        nc0 = nn0; nc1 = nn1;

        __builtin_amdgcn_wave_barrier();   // protect Zlds WAR before next scatter
    }

    float4* xout = (float4*)(outX + (size_t)part * 32 + 8 * q);
    xout[0] = make_float4(X[0], X[1], X[2], X[3]);
    xout[1] = make_float4(X[4], X[5], X[6], X[7]);
    if (q == 0) outV[part] = V;
}

extern "C" void kernel_launch(void* const* d_in, const int* in_sizes, int n_in,
                              void* d_out, int out_size, void* d_ws, size_t ws_size,
                              hipStream_t stream) {
    const float* obs   = (const float*)d_in[0];
    const float* x0    = (const float*)d_in[1];
    const float* v0    = (const float*)d_in[2];
    const float* noise = (const float*)d_in[3];
    const float* W1    = (const float*)d_in[4];
    const float* b1    = (const float*)d_in[5];
    const float* W2    = (const float*)d_in[6];
    const float* b2    = (const float*)d_in[7];
    const float* th    = (const float*)d_in[8];
    const int*   oi    = (const int*)d_in[9];
    const int*   cr    = (const int*)d_in[10];

    float* outX = (float*)d_out;
    float* outV = outX + (size_t)NPART * 32;

    dim3 grid(NPART / 64);   // 512 blocks x 4 waves x 16 particles
    fused_sde_mfma<<<grid, BLOCK, 0, stream>>>(obs, x0, v0, noise, W1, b1, W2, b2,
                                               th, oi, cr, outX, outV);
}